// Round 3
// baseline (670.791 us; speedup 1.0000x reference)
//
#include <hip/hip_runtime.h>
#include <math.h>

#define N_BINS 15

typedef float vfloat4 __attribute__((ext_vector_type(4)));

// Online-softmax ECCE rows kernel.
// Layout: 4 lanes per row (a "quad"), 16 rows per wave, 64 rows per block.
// Each lane walks float4s j = 4*i + q of its row, maintaining running
// (max m, first-occurrence argmax idx, rescaled denom s) online.
// Loads rotate through 4 named registers -> 3-4 loads in flight per lane at
// all times (~56 B/lane; ~100 KB/CU at full occupancy) -> latency-immune
// streaming, vs. the old wave-per-row's 64 B/wave burst + dead compute phase.
// Requires C % 4 == 0 and C >= 16 (true here: C = 1000).
__global__ __launch_bounds__(256) void ecce_rows_kernel(
    const float* __restrict__ logits,
    const int* __restrict__ labels,
    float* __restrict__ seg_buf,   // C * N_BINS floats, pre-zeroed
    int N, int C)
{
    const int lane = threadIdx.x & 63;
    const int wv   = threadIdx.x >> 6;
    const int q    = lane & 3;          // position within quad
    const int rw   = lane >> 2;         // row within wave (0..15)

    int row = (blockIdx.x * 4 + wv) * 16 + rw;
    const bool rvalid = row < N;
    row = rvalid ? row : (N - 1);

    const int n4    = C >> 2;           // float4s per row (250)
    const int nstep = (n4 + 3) >> 2;    // float4 steps per lane (63)
    const vfloat4* __restrict__ rp = (const vfloat4*)(logits + (size_t)row * (size_t)C);
    const int label = labels[row];      // quad-uniform; issued early

    float m = -INFINITY, s = 0.0f;
    int idx = 0x7fffffff;

// Clamped load: last-step lanes re-read float4 (n4-1) (in-bounds, L1-hit).
#define LD(I) (rp[((4*(I) + q) < n4) ? (4*(I) + q) : (n4 - 1)])
// Online update: exact running max, exact first-occurrence argmax
// (strictly-greater update keeps earliest index), rescaled denominator.
// s-update uses pre-update m; exp(0)=1 exactly when max unchanged.
#define STEP_BODY(x0, x1, x2, x3, I) do {                                   \
        const int c0 = 16*(I) + 4*q;                                        \
        const float m4 = fmaxf(fmaxf((x0),(x1)), fmaxf((x2),(x3)));         \
        const float mn = fmaxf(m, m4);                                      \
        s = s * __expf(m - mn)                                              \
          + (__expf((x0)-mn) + __expf((x1)-mn)                              \
           + __expf((x2)-mn) + __expf((x3)-mn));                            \
        idx = ((x0) > m) ? c0     : idx; float t = fmaxf(m,(x0));           \
        idx = ((x1) > t) ? c0 + 1 : idx; t = fmaxf(t,(x1));                 \
        idx = ((x2) > t) ? c0 + 2 : idx; t = fmaxf(t,(x2));                 \
        idx = ((x3) > t) ? c0 + 3 : idx;                                    \
        m = mn;                                                             \
    } while (0)
#define STEP(P, I)  STEP_BODY((P).x, (P).y, (P).z, (P).w, I)
#define STEPM(P, I) do {                                                    \
        const bool ok = (4*(I) + q) < n4;                                   \
        const float y0 = ok ? (P).x : -INFINITY;                            \
        const float y1 = ok ? (P).y : -INFINITY;                            \
        const float y2 = ok ? (P).z : -INFINITY;                            \
        const float y3 = ok ? (P).w : -INFINITY;                            \
        STEP_BODY(y0, y1, y2, y3, I);                                       \
    } while (0)

    vfloat4 p0 = LD(0), p1 = LD(1), p2 = LD(2), p3 = LD(3);
    int i = 0;
    // Main loop: computes steps i..i+3 (always fully valid: j <= n4-14),
    // loads steps i+4..i+7 (clamped only at the very last step).
    for (; i + 8 <= nstep; i += 4) {
        STEP(p0, i + 0); p0 = LD(i + 4);
        STEP(p1, i + 1); p1 = LD(i + 5);
        STEP(p2, i + 2); p2 = LD(i + 6);
        STEP(p3, i + 3); p3 = LD(i + 7);
    }
    // Epilogue: rem = nstep - i in [4,7]; at most 3 tail loads; all masked.
    {
        const int rem = nstep - i;
        vfloat4 p4 = p3, p5 = p3, p6 = p3;
        if (rem > 4) p4 = LD(i + 4);
        if (rem > 5) p5 = LD(i + 5);
        if (rem > 6) p6 = LD(i + 6);
        STEPM(p0, i + 0);
        STEPM(p1, i + 1);
        STEPM(p2, i + 2);
        STEPM(p3, i + 3);
        if (rem > 4) STEPM(p4, i + 4);
        if (rem > 5) STEPM(p5, i + 5);
        if (rem > 6) STEPM(p6, i + 6);
    }
#undef LD
#undef STEP_BODY
#undef STEP
#undef STEPM

    // Quad reduction (offsets 1,2 stay inside the quad).
    // Fused (max, first-occurrence argmax): hierarchical min-index-among-max.
    const float ml = m;
    #pragma unroll
    for (int off = 1; off <= 2; off <<= 1) {
        const float mo = __shfl_xor(m, off, 64);
        const int   io = __shfl_xor(idx, off, 64);
        const int imin = (io < idx) ? io : idx;
        idx = (mo > m) ? io : ((mo == m) ? imin : idx);
        m   = fmaxf(m, mo);
    }
    // Rebase each lane's denom to the row max, then deterministic quad sum.
    float st = s * __expf(ml - m);
    st += __shfl_xor(st, 1, 64);
    st += __shfl_xor(st, 2, 64);

    if (q == 0 && rvalid) {
        const float conf = 1.0f / st;              // exp(m-m)/sum
        int bin = (int)ceilf(conf * (float)N_BINS) - 1;
        bin = bin < 0 ? 0 : (bin > N_BINS - 1 ? N_BINS - 1 : bin);
        const float acc = (idx == label) ? 1.0f : 0.0f;
        atomicAdd(&seg_buf[label * N_BINS + bin], conf - acc);
    }
}

// Single-block final reduction: ecce = sum(|seg_buf[i]|) / N.
// float4 loads; 16 waves for MLP over the 15000-element buffer.
__global__ __launch_bounds__(1024) void ecce_final_kernel(
    const float* __restrict__ seg_buf, float* __restrict__ out,
    int nseg, float invN)
{
    __shared__ float sdata[16];
    const vfloat4* __restrict__ sb4 = (const vfloat4*)seg_buf;
    const int n4 = nseg >> 2;
    float s = 0.0f;
    for (int i = threadIdx.x; i < n4; i += 1024) {
        const vfloat4 v = sb4[i];
        s += fabsf(v.x) + fabsf(v.y) + fabsf(v.z) + fabsf(v.w);
    }
    for (int i = (n4 << 2) + threadIdx.x; i < nseg; i += 1024)
        s += fabsf(seg_buf[i]);
    #pragma unroll
    for (int off = 32; off >= 1; off >>= 1) s += __shfl_xor(s, off, 64);
    const int lane = threadIdx.x & 63;
    const int wvv  = threadIdx.x >> 6;
    if (lane == 0) sdata[wvv] = s;
    __syncthreads();
    if (threadIdx.x == 0) {
        float t = 0.0f;
        #pragma unroll
        for (int k = 0; k < 16; ++k) t += sdata[k];
        out[0] = t * invN;
    }
}

extern "C" void kernel_launch(void* const* d_in, const int* in_sizes, int n_in,
                              void* d_out, int out_size, void* d_ws, size_t ws_size,
                              hipStream_t stream) {
    const float* logits = (const float*)d_in[0];
    const int*   labels = (const int*)d_in[1];
    const int N = in_sizes[1];
    const int C = in_sizes[0] / N;
    const int nseg = C * N_BINS;

    float* seg_buf = (float*)d_ws;
    (void)hipMemsetAsync(seg_buf, 0, (size_t)nseg * sizeof(float), stream);

    // 64 rows per block (4 waves x 16 rows); N=131072 -> 2048 blocks = 8/CU.
    const int blocks = (N + 63) / 64;
    ecce_rows_kernel<<<blocks, 256, 0, stream>>>(logits, labels, seg_buf, N, C);

    ecce_final_kernel<<<1, 1024, 0, stream>>>(seg_buf, (float*)d_out, nseg, 1.0f / (float)N);
}